// Round 2
// baseline (41.936 us; speedup 1.0000x reference)
//
#include <hip/hip_runtime.h>

#define BSZ 64
#define LMAX 128
#define DIM 2048

// ---------------- kernel 1: projections (+ accumulator init) ----------------
// 256-thread blocks = 4 waves; each wave handles 4 consecutive positions,
// reusing one W fragment across 4 h rows. Grid = BSZ*LMAX/16 = 512 blocks.
__global__ __launch_bounds__(256) void proj_kernel(
        const float* __restrict__ enc,
        const float* __restrict__ W,
        float* __restrict__ proj,
        float* __restrict__ accum,
        int* __restrict__ count,
        int* __restrict__ done) {
    if (blockIdx.x == 0 && threadIdx.x == 0) {
        accum[0] = 0.0f;
        count[0] = 0;
        done[0]  = 0;
    }

    const int wid  = threadIdx.x >> 6;
    const int lane = threadIdx.x & 63;
    const int p0   = (blockIdx.x * 4 + wid) * 4;   // first of 4 positions

    const float4* h4 = (const float4*)enc;   // [pos * 512 + idx]
    const float4* W4 = (const float4*)W;     // W is [2*DIM, 2] row-major

    float a[4][4];
    #pragma unroll
    for (int q = 0; q < 4; ++q)
        #pragma unroll
        for (int o = 0; o < 4; ++o) a[q][o] = 0.f;

    #pragma unroll
    for (int it = 0; it < 8; ++it) {
        const int idx = it * 64 + lane;            // float4 index in row, 0..511
        // left weights: rows 4idx..4idx+3 -> float4 [2idx, 2idx+1]
        const float4 w0 = W4[idx * 2];
        const float4 w1 = W4[idx * 2 + 1];
        // right weights: rows 2048+4idx.. -> float4 [1024+2idx, ...]
        const float4 w2 = W4[1024 + idx * 2];
        const float4 w3 = W4[1024 + idx * 2 + 1];
        #pragma unroll
        for (int q = 0; q < 4; ++q) {
            const float4 h = h4[(size_t)(p0 + q) * (DIM / 4) + idx];
            a[q][0] += h.x * w0.x + h.y * w0.z + h.z * w1.x + h.w * w1.z;
            a[q][1] += h.x * w0.y + h.y * w0.w + h.z * w1.y + h.w * w1.w;
            a[q][2] += h.x * w2.x + h.y * w2.z + h.z * w3.x + h.w * w3.z;
            a[q][3] += h.x * w2.y + h.y * w2.w + h.z * w3.y + h.w * w3.w;
        }
    }

    // 64-lane butterfly reduction of all 16 accumulators
    #pragma unroll
    for (int off = 32; off >= 1; off >>= 1)
        #pragma unroll
        for (int q = 0; q < 4; ++q)
            #pragma unroll
            for (int o = 0; o < 4; ++o)
                a[q][o] += __shfl_xor(a[q][o], off);

    if (lane == 0) {
        #pragma unroll
        for (int q = 0; q < 4; ++q) {
            float4 v;
            v.x = a[q][0]; v.y = a[q][1]; v.z = a[q][2]; v.w = a[q][3];
            ((float4*)proj)[p0 + q] = v;
        }
    }
}

// ---------------- kernel 2: pairwise NLL reduction + finalize ----------------
// One block per batch; last finished block writes the final scalar.
__global__ __launch_bounds__(256) void loss_kernel(
        const int* __restrict__ mask,
        const float* __restrict__ proj,
        const float* __restrict__ bias,
        float* __restrict__ accum,
        int* __restrict__ count,
        int* __restrict__ done,
        float* __restrict__ out) {
    __shared__ float4 s_proj[LMAX];
    __shared__ float  s_w[4];
    __shared__ int    s_m[4];

    const int b   = blockIdx.x;
    const int tid = threadIdx.x;

    if (tid < LMAX) s_proj[tid] = ((const float4*)proj)[b * LMAX + tid];

    // turn length via shuffle reduce of the prefix mask
    int m = (tid < LMAX) ? mask[b * LMAX + tid] : 0;
    #pragma unroll
    for (int off = 32; off >= 1; off >>= 1) m += __shfl_xor(m, off);
    if ((tid & 63) == 0) s_m[tid >> 6] = m;
    __syncthreads();

    const int   T  = s_m[0] + s_m[1] + s_m[2] + s_m[3];
    const float b0 = bias[0];
    const float b1 = bias[1];

    float local = 0.f;
    for (int t = tid; t < LMAX * LMAX; t += 256) {
        const int j = t >> 7;
        const int k = t & (LMAX - 1);
        if (k < j && j < T) {
            const float4 pj = s_proj[j];
            const float4 pk = s_proj[k];
            const float l0 = pj.x + pk.z + b0;
            const float l1 = pj.y + pk.w + b1;
            const bool  pos = (k == j - 1);
            const float chosen = pos ? l1 : l0;
            const float other  = pos ? l0 : l1;
            // lse - chosen == log(1 + exp(other - chosen))
            local += log1pf(__expf(other - chosen));
        }
    }

    #pragma unroll
    for (int off = 32; off >= 1; off >>= 1) local += __shfl_xor(local, off);
    if ((tid & 63) == 0) s_w[tid >> 6] = local;
    __syncthreads();

    if (tid == 0) {
        atomicAdd(accum, s_w[0] + s_w[1] + s_w[2] + s_w[3]);
        atomicAdd(count, T * (T - 1) / 2);
        __threadfence();
        const int prev = atomicAdd(done, 1);
        if (prev == BSZ - 1) {
            // all blocks' atomics are visible; read via atomic fetch
            const float s = atomicAdd(accum, 0.0f);
            const int   c = atomicAdd(count, 0);
            out[0] = s / (float)(c > 1 ? c : 1);
        }
    }
}

extern "C" void kernel_launch(void* const* d_in, const int* in_sizes, int n_in,
                              void* d_out, int out_size, void* d_ws, size_t ws_size,
                              hipStream_t stream) {
    const float* enc  = (const float*)d_in[0];  // [BSZ, LMAX, DIM] fp32
    const int*   mask = (const int*)d_in[1];    // [BSZ, LMAX] int32
    const float* W    = (const float*)d_in[2];  // [2*DIM, 2] fp32
    const float* bias = (const float*)d_in[3];  // [2] fp32
    float* out = (float*)d_out;

    float* proj  = (float*)d_ws;                 // BSZ*LMAX*4 floats
    float* accum = proj + BSZ * LMAX * 4;
    int*   count = (int*)(accum + 1);
    int*   done  = count + 1;

    proj_kernel<<<(BSZ * LMAX) / 16, 256, 0, stream>>>(enc, W, proj, accum, count, done);
    loss_kernel<<<BSZ, 256, 0, stream>>>(mask, proj, bias, accum, count, done, out);
}

// Round 3
// 30.679 us; speedup vs baseline: 1.3670x; 1.3670x over previous
//
#include <hip/hip_runtime.h>

#define BSZ 64
#define LMAX 128
#define DIM 2048

// ---------------- kernel 1: projections (+ accumulator init) ----------------
// One wave per position: 2048 blocks x 256 threads (4 waves) = 8192 waves,
// 8 blocks/CU = 32 waves/CU (full occupancy) to hide the 64 MB HBM stream.
__global__ __launch_bounds__(256) void proj_kernel(
        const float* __restrict__ enc,
        const float* __restrict__ W,
        float* __restrict__ proj,
        float* __restrict__ accum,
        int* __restrict__ count,
        int* __restrict__ done) {
    if (blockIdx.x == 0 && threadIdx.x == 0) {
        accum[0] = 0.0f;
        count[0] = 0;
        done[0]  = 0;
    }

    const int wid  = threadIdx.x >> 6;
    const int lane = threadIdx.x & 63;
    const int p    = blockIdx.x * 4 + wid;       // position index 0..8191

    const float4* __restrict__ h4 = (const float4*)(enc + (size_t)p * DIM);
    const float4* __restrict__ W4 = (const float4*)W;   // [2*DIM, 2] row-major

    float a0 = 0.f, a1 = 0.f, a2 = 0.f, a3 = 0.f;
    #pragma unroll
    for (int it = 0; it < 8; ++it) {
        const int idx = it * 64 + lane;          // float4 index in row, 0..511
        const float4 h  = h4[idx];
        const float4 w0 = W4[idx * 2];           // left rows 4idx..4idx+3
        const float4 w1 = W4[idx * 2 + 1];
        const float4 w2 = W4[1024 + idx * 2];    // right rows (+DIM)
        const float4 w3 = W4[1024 + idx * 2 + 1];
        a0 += h.x * w0.x + h.y * w0.z + h.z * w1.x + h.w * w1.z;
        a1 += h.x * w0.y + h.y * w0.w + h.z * w1.y + h.w * w1.w;
        a2 += h.x * w2.x + h.y * w2.z + h.z * w3.x + h.w * w3.z;
        a3 += h.x * w2.y + h.y * w2.w + h.z * w3.y + h.w * w3.w;
    }
    #pragma unroll
    for (int off = 32; off >= 1; off >>= 1) {
        a0 += __shfl_xor(a0, off);
        a1 += __shfl_xor(a1, off);
        a2 += __shfl_xor(a2, off);
        a3 += __shfl_xor(a3, off);
    }
    if (lane == 0) {
        float4 v; v.x = a0; v.y = a1; v.z = a2; v.w = a3;
        ((float4*)proj)[p] = v;
    }
}

// ---------------- kernel 2: pairwise NLL reduction + finalize ----------------
__global__ __launch_bounds__(256) void loss_kernel(
        const int* __restrict__ mask,
        const float* __restrict__ proj,
        const float* __restrict__ bias,
        float* __restrict__ accum,
        int* __restrict__ count,
        int* __restrict__ done,
        float* __restrict__ out) {
    __shared__ float4 s_proj[LMAX];
    __shared__ float  s_w[4];
    __shared__ int    s_m[4];

    const int b   = blockIdx.x;
    const int tid = threadIdx.x;

    if (tid < LMAX) s_proj[tid] = ((const float4*)proj)[b * LMAX + tid];

    int m = (tid < LMAX) ? mask[b * LMAX + tid] : 0;
    #pragma unroll
    for (int off = 32; off >= 1; off >>= 1) m += __shfl_xor(m, off);
    if ((tid & 63) == 0) s_m[tid >> 6] = m;
    __syncthreads();

    const int   T  = s_m[0] + s_m[1] + s_m[2] + s_m[3];
    const float b0 = bias[0];
    const float b1 = bias[1];

    // only j in [0, T) matter; bound the loop at T*128 pairs
    float local = 0.f;
    const int tmax = T << 7;
    for (int t = tid; t < tmax; t += 256) {
        const int j = t >> 7;
        const int k = t & (LMAX - 1);
        if (k < j) {
            const float4 pj = s_proj[j];
            const float4 pk = s_proj[k];
            const float l0 = pj.x + pk.z + b0;
            const float l1 = pj.y + pk.w + b1;
            const bool  pos = (k == j - 1);
            // nll = lse - chosen = softplus(other - chosen), stable branch-free
            const float d  = pos ? (l0 - l1) : (l1 - l0);
            local += fmaxf(d, 0.f) + __logf(1.f + __expf(-fabsf(d)));
        }
    }

    #pragma unroll
    for (int off = 32; off >= 1; off >>= 1) local += __shfl_xor(local, off);
    if ((tid & 63) == 0) s_w[tid >> 6] = local;
    __syncthreads();

    if (tid == 0) {
        atomicAdd(accum, s_w[0] + s_w[1] + s_w[2] + s_w[3]);
        atomicAdd(count, T * (T - 1) / 2);
        __threadfence();
        const int prev = atomicAdd(done, 1);
        if (prev == BSZ - 1) {
            const float s = atomicAdd(accum, 0.0f);
            const int   c = atomicAdd(count, 0);
            out[0] = s / (float)(c > 1 ? c : 1);
        }
    }
}

extern "C" void kernel_launch(void* const* d_in, const int* in_sizes, int n_in,
                              void* d_out, int out_size, void* d_ws, size_t ws_size,
                              hipStream_t stream) {
    const float* enc  = (const float*)d_in[0];  // [BSZ, LMAX, DIM] fp32
    const int*   mask = (const int*)d_in[1];    // [BSZ, LMAX] int32
    const float* W    = (const float*)d_in[2];  // [2*DIM, 2] fp32
    const float* bias = (const float*)d_in[3];  // [2] fp32
    float* out = (float*)d_out;

    float* proj  = (float*)d_ws;                // BSZ*LMAX*4 floats
    float* accum = proj + BSZ * LMAX * 4;
    int*   count = (int*)(accum + 1);
    int*   done  = count + 1;

    proj_kernel<<<(BSZ * LMAX) / 4, 256, 0, stream>>>(enc, W, proj, accum, count, done);
    loss_kernel<<<BSZ, 256, 0, stream>>>(mask, proj, bias, accum, count, done, out);
}

// Round 4
// 29.602 us; speedup vs baseline: 1.4167x; 1.0364x over previous
//
#include <hip/hip_runtime.h>

#define BSZ 64
#define LMAX 128
#define DIM 2048

// ---------------- kernel 1: projections (+ accumulator init) ----------------
// Blocks of 512 threads = 8 waves, one position per wave. Grid = 8192/8 = 1024.
// W (32 KB) staged once per block into LDS as 4 SoA float4 arrays ->
// inner loop is 1 global float4 (pure h stream) + 4 conflict-free ds_read_b128.
// LDS 32 KB/block -> 4 blocks/CU = 32 waves/CU (full occupancy if VGPR <= 64).
__global__ __launch_bounds__(512) void proj_kernel(
        const float* __restrict__ enc,
        const float* __restrict__ W,
        float* __restrict__ proj,
        float* __restrict__ accum,
        int* __restrict__ count,
        int* __restrict__ done) {
    if (blockIdx.x == 0 && threadIdx.x == 0) {
        accum[0] = 0.0f;
        count[0] = 0;
        done[0]  = 0;
    }

    __shared__ float4 sW[4][512];   // [w0,w1,w2,w3] indexed by idx (8 KB each)

    const float4* __restrict__ W4 = (const float4*)W;   // [2*DIM, 2] row-major
    {
        const int i = threadIdx.x;          // 512 threads cover 512 idx slots
        sW[0][i] = W4[i * 2];               // left rows 4i..4i+3, cols interleaved
        sW[1][i] = W4[i * 2 + 1];
        sW[2][i] = W4[1024 + i * 2];        // right rows (+DIM)
        sW[3][i] = W4[1024 + i * 2 + 1];
    }
    __syncthreads();

    const int wid  = threadIdx.x >> 6;
    const int lane = threadIdx.x & 63;
    const int p    = blockIdx.x * 8 + wid;       // position index 0..8191

    const float4* __restrict__ h4 = (const float4*)(enc + (size_t)p * DIM);

    float a0 = 0.f, a1 = 0.f, a2 = 0.f, a3 = 0.f;
    #pragma unroll
    for (int it = 0; it < 8; ++it) {
        const int idx = it * 64 + lane;          // float4 index in row, 0..511
        const float4 h  = h4[idx];
        const float4 w0 = sW[0][idx];
        const float4 w1 = sW[1][idx];
        const float4 w2 = sW[2][idx];
        const float4 w3 = sW[3][idx];
        a0 += h.x * w0.x + h.y * w0.z + h.z * w1.x + h.w * w1.z;
        a1 += h.x * w0.y + h.y * w0.w + h.z * w1.y + h.w * w1.w;
        a2 += h.x * w2.x + h.y * w2.z + h.z * w3.x + h.w * w3.z;
        a3 += h.x * w2.y + h.y * w2.w + h.z * w3.y + h.w * w3.w;
    }
    #pragma unroll
    for (int off = 32; off >= 1; off >>= 1) {
        a0 += __shfl_xor(a0, off);
        a1 += __shfl_xor(a1, off);
        a2 += __shfl_xor(a2, off);
        a3 += __shfl_xor(a3, off);
    }
    if (lane == 0) {
        float4 v; v.x = a0; v.y = a1; v.z = a2; v.w = a3;
        ((float4*)proj)[p] = v;
    }
}

// ---------------- kernel 2: pairwise NLL reduction + finalize ----------------
__global__ __launch_bounds__(256) void loss_kernel(
        const int* __restrict__ mask,
        const float* __restrict__ proj,
        const float* __restrict__ bias,
        float* __restrict__ accum,
        int* __restrict__ count,
        int* __restrict__ done,
        float* __restrict__ out) {
    __shared__ float4 s_proj[LMAX];
    __shared__ float  s_w[4];
    __shared__ int    s_m[4];

    const int b   = blockIdx.x;
    const int tid = threadIdx.x;

    if (tid < LMAX) s_proj[tid] = ((const float4*)proj)[b * LMAX + tid];

    int m = (tid < LMAX) ? mask[b * LMAX + tid] : 0;
    #pragma unroll
    for (int off = 32; off >= 1; off >>= 1) m += __shfl_xor(m, off);
    if ((tid & 63) == 0) s_m[tid >> 6] = m;
    __syncthreads();

    const int   T  = s_m[0] + s_m[1] + s_m[2] + s_m[3];
    const float b0 = bias[0];
    const float b1 = bias[1];

    float local = 0.f;
    const int tmax = T << 7;
    for (int t = tid; t < tmax; t += 256) {
        const int j = t >> 7;
        const int k = t & (LMAX - 1);
        if (k < j) {
            const float4 pj = s_proj[j];
            const float4 pk = s_proj[k];
            const float l0 = pj.x + pk.z + b0;
            const float l1 = pj.y + pk.w + b1;
            const bool  pos = (k == j - 1);
            const float d  = pos ? (l0 - l1) : (l1 - l0);
            local += fmaxf(d, 0.f) + __logf(1.f + __expf(-fabsf(d)));
        }
    }

    #pragma unroll
    for (int off = 32; off >= 1; off >>= 1) local += __shfl_xor(local, off);
    if ((tid & 63) == 0) s_w[tid >> 6] = local;
    __syncthreads();

    if (tid == 0) {
        atomicAdd(accum, s_w[0] + s_w[1] + s_w[2] + s_w[3]);
        atomicAdd(count, T * (T - 1) / 2);
        __threadfence();
        const int prev = atomicAdd(done, 1);
        if (prev == BSZ - 1) {
            const float s = atomicAdd(accum, 0.0f);
            const int   c = atomicAdd(count, 0);
            out[0] = s / (float)(c > 1 ? c : 1);
        }
    }
}

extern "C" void kernel_launch(void* const* d_in, const int* in_sizes, int n_in,
                              void* d_out, int out_size, void* d_ws, size_t ws_size,
                              hipStream_t stream) {
    const float* enc  = (const float*)d_in[0];  // [BSZ, LMAX, DIM] fp32
    const int*   mask = (const int*)d_in[1];    // [BSZ, LMAX] int32
    const float* W    = (const float*)d_in[2];  // [2*DIM, 2] fp32
    const float* bias = (const float*)d_in[3];  // [2] fp32
    float* out = (float*)d_out;

    float* proj  = (float*)d_ws;                // BSZ*LMAX*4 floats
    float* accum = proj + BSZ * LMAX * 4;
    int*   count = (int*)(accum + 1);
    int*   done  = count + 1;

    proj_kernel<<<(BSZ * LMAX) / 8, 512, 0, stream>>>(enc, W, proj, accum, count, done);
    loss_kernel<<<BSZ, 256, 0, stream>>>(mask, proj, bias, accum, count, done, out);
}